// Round 1
// baseline (70.694 us; speedup 1.0000x reference)
//
#include <hip/hip_runtime.h>
#include <hip/hip_bf16.h>
#include <stdint.h>

// Real spherical harmonics basis, degree 4 (l = 0..3), 16 coefficients.
// Memory-bound streaming map: [B,3] f32 -> [B,16] f32.
// Mapping: one thread per output float4 (point = tid>>2, quarter = tid&3)
// => writes are perfectly lane-contiguous (16 B/lane, 1 KiB/wave/instr).

#define C0    0.28209479177387814f
#define C1    0.48860251190291987f
#define C2_0  1.0925484305920792f
#define C2_2a 0.94617469575755997f
#define C2_2b 0.31539156525251999f
#define C2_4  0.54627421529603959f
#define C3_0  0.59004358992664352f
#define C3_1  2.8906114426405538f
#define C3_2  0.45704579946446572f
#define C3_3  0.3731763325901154f
#define C3_5  1.445305721320277f

__global__ void __launch_bounds__(256) sh_encode_kernel(
    const float* __restrict__ in,        // [B,3]
    const uint32_t* __restrict__ size_raw, // scalar (value 1; int or float bits)
    float4* __restrict__ out4,           // [B*4] float4 == [B,16] float
    int B)
{
    // Decode the scalar `size` robustly: int bits (1) or float bits (1.0f).
    uint32_t sb = *size_raw;
    float s = (sb == 0x3F800000u) ? 1.0f : (float)(int)sb;
    float inv = 1.0f / s;

    int total = B * 4;
    int stride = gridDim.x * blockDim.x;
    for (int tid = blockIdx.x * blockDim.x + threadIdx.x; tid < total; tid += stride) {
        int pt = tid >> 2;
        int q  = tid & 3;

        const float* p = in + (size_t)pt * 3;
        float x = p[0] * inv;
        float y = p[1] * inv;
        float z = p[2] * inv;

        float4 r;
        if (q == 0) {
            r.x = C0;
            r.y = -C1 * y;
            r.z =  C1 * z;
            r.w = -C1 * x;
        } else if (q == 1) {
            float xy = x * y, yz = y * z, xz = x * z, zz = z * z;
            r.x =  C2_0 * xy;
            r.y = -C2_0 * yz;
            r.z =  C2_2a * zz - C2_2b;
            r.w = -C2_0 * xz;
        } else if (q == 2) {
            float xx = x * x, yy = y * y, zz = z * z;
            r.x = C2_4 * (xx - yy);
            r.y = C3_0 * y * (-3.0f * xx + yy);
            r.z = C3_1 * (x * y) * z;
            r.w = C3_2 * y * (1.0f - 5.0f * zz);
        } else {
            float xx = x * x, yy = y * y, zz = z * z;
            r.x = C3_3 * z * (5.0f * zz - 3.0f);
            r.y = C3_2 * x * (1.0f - 5.0f * zz);
            r.z = C3_5 * z * (xx - yy);
            r.w = C3_0 * x * (-xx + 3.0f * yy);
        }
        out4[tid] = r;
    }
}

extern "C" void kernel_launch(void* const* d_in, const int* in_sizes, int n_in,
                              void* d_out, int out_size, void* d_ws, size_t ws_size,
                              hipStream_t stream) {
    const float* in = (const float*)d_in[0];
    const uint32_t* size_raw = (const uint32_t*)d_in[1];
    float4* out4 = (float4*)d_out;

    int B = in_sizes[0] / 3;   // 4194304
    int blocks = 2048;         // grid-stride; ~8 float4-outputs per thread
    sh_encode_kernel<<<blocks, 256, 0, stream>>>(in, size_raw, out4, B);
}

// Round 2
// 60.695 us; speedup vs baseline: 1.1647x; 1.1647x over previous
//
#include <hip/hip_runtime.h>
#include <hip/hip_bf16.h>
#include <stdint.h>

// Real spherical harmonics basis, degree 4 (l = 0..3), 16 coefficients.
// [B,3] f32 -> [B,16] f32, B = 4194304. Memory-bound streaming map.
//
// Round-2 structure: one block per 256-point chunk.
//  - threads 0..191 stage the chunk's input (192 float4 = 768 floats) into
//    LDS via perfectly-coalesced float4 loads
//  - one barrier
//  - each thread writes 4 output float4s (out index = chunk*1024 + j*256 + t),
//    always the same quarter q = t&3; xyz read from LDS (stride-3 -> banks
//    conflict-free mod 32, quad-broadcast free)
// Writes are perfectly lane-contiguous float4 streams.

#define C0    0.28209479177387814f
#define C1    0.48860251190291987f
#define C2_0  1.0925484305920792f
#define C2_2a 0.94617469575755997f
#define C2_2b 0.31539156525251999f
#define C2_4  0.54627421529603959f
#define C3_0  0.59004358992664352f
#define C3_1  2.8906114426405538f
#define C3_2  0.45704579946446572f
#define C3_3  0.3731763325901154f
#define C3_5  1.445305721320277f

__global__ void __launch_bounds__(256) sh_encode_kernel(
    const float4* __restrict__ in4,        // [B*3/4] float4 view of [B,3]
    const uint32_t* __restrict__ size_raw, // scalar `size` (value 1)
    float4* __restrict__ out4)             // [B*4] float4 == [B,16] float
{
    // Decode scalar `size`: int bits or float bits both map to its value.
    uint32_t sb = *size_raw;
    float s = (sb == 0x3F800000u) ? 1.0f : (float)(int)sb;
    float inv = 1.0f / s;

    __shared__ float smem[768];            // 256 points * 3 floats

    int t = threadIdx.x;
    size_t chunk = blockIdx.x;             // one chunk = 256 points

    // Stage input: 192 coalesced float4 loads.
    if (t < 192) {
        reinterpret_cast<float4*>(smem)[t] = in4[chunk * 192 + t];
    }
    __syncthreads();

    int q     = t & 3;                     // which quarter of the 16 coeffs
    int pbase = t >> 2;                    // point-within-64 group
    size_t out_base = chunk * 1024 + (size_t)t;

    #pragma unroll
    for (int j = 0; j < 4; ++j) {
        int pl = j * 64 + pbase;           // local point index 0..255
        float x = smem[pl * 3 + 0] * inv;
        float y = smem[pl * 3 + 1] * inv;
        float z = smem[pl * 3 + 2] * inv;

        float4 r;
        if (q == 0) {
            r.x = C0;
            r.y = -C1 * y;
            r.z =  C1 * z;
            r.w = -C1 * x;
        } else if (q == 1) {
            float xy = x * y, yz = y * z, xz = x * z, zz = z * z;
            r.x =  C2_0 * xy;
            r.y = -C2_0 * yz;
            r.z =  C2_2a * zz - C2_2b;
            r.w = -C2_0 * xz;
        } else if (q == 2) {
            float xx = x * x, yy = y * y, zz = z * z;
            r.x = C2_4 * (xx - yy);
            r.y = C3_0 * y * (-3.0f * xx + yy);
            r.z = C3_1 * (x * y) * z;
            r.w = C3_2 * y * (1.0f - 5.0f * zz);
        } else {
            float xx = x * x, yy = y * y, zz = z * z;
            r.x = C3_3 * z * (5.0f * zz - 3.0f);
            r.y = C3_2 * x * (1.0f - 5.0f * zz);
            r.z = C3_5 * z * (xx - yy);
            r.w = C3_0 * x * (-xx + 3.0f * yy);
        }
        out4[out_base + (size_t)j * 256] = r;
    }
}

extern "C" void kernel_launch(void* const* d_in, const int* in_sizes, int n_in,
                              void* d_out, int out_size, void* d_ws, size_t ws_size,
                              hipStream_t stream) {
    const float4* in4 = (const float4*)d_in[0];
    const uint32_t* size_raw = (const uint32_t*)d_in[1];
    float4* out4 = (float4*)d_out;

    int B = in_sizes[0] / 3;               // 4194304
    int blocks = B / 256;                  // 16384 chunks, exact
    sh_encode_kernel<<<blocks, 256, 0, stream>>>(in4, size_raw, out4);
}